// Round 11
// baseline (214.807 us; speedup 1.0000x reference)
//
#include <hip/hip_runtime.h>

#define HID 64
#define DIN 128
#define NBLK 512                // blocks for the build pass
#define CSH 14                  // slab capacity shift: 16384 entries per bucket
#define CAP (1 << CSH)
#define PAD 68                  // float4-aligned LDS row stride

typedef unsigned long long ull;
typedef unsigned short u16;

static __device__ __forceinline__ u16 f2bf(float f) {
  unsigned u = __float_as_uint(f);
  unsigned lsb = (u >> 16) & 1u;
  u += 0x7fffu + lsb;
  return (u16)(u >> 16);
}

// ============ gemm tile (K1 gemm1 role): 512 threads, 64x64, self-transposing W ====
// W staging lane map: qd wave-uniform, j lane-sweep -> conflict-free (round-7 fix).

template <int K>
__device__ __forceinline__ void gemm_tile(const float* __restrict__ X,
                                          const float* __restrict__ W,
                                          u16* __restrict__ out,
                                          float* XT, float* WL,
                                          int n0, int n_nodes, int tid) {
  const int tx = tid & 15;
  const int ty = tid >> 4;                // 0..31
  float acc[2][4] = {{0.f}};

  for (int ph = 0; ph < K / 64; ++ph) {
    const int d0 = ph * 64;
    __syncthreads();
#pragma unroll
    for (int k = 0; k < 2; ++k) {         // 1024 float4 slots: 64 rows x 16 quads
      int f = tid + k * 512;
      int r = f >> 4, q = f & 15;
      int n = n0 + r;
      float4 xv = (n < n_nodes)
        ? *reinterpret_cast<const float4*>(&X[(size_t)n * K + d0 + 4 * q])
        : make_float4(0.f, 0.f, 0.f, 0.f);
      *reinterpret_cast<float4*>(&XT[r * PAD + 4 * q]) = xv;
    }
#pragma unroll
    for (int k = 0; k < 2; ++k) {         // 1024 slots: 16 d-quads x 64 j
      int gq = tid + k * 512;
      int qd = gq >> 6, j = gq & 63;
      float4 wv = *reinterpret_cast<const float4*>(&W[(size_t)j * K + d0 + 4 * qd]);
      WL[(4 * qd + 0) * PAD + j] = wv.x;
      WL[(4 * qd + 1) * PAD + j] = wv.y;
      WL[(4 * qd + 2) * PAD + j] = wv.z;
      WL[(4 * qd + 3) * PAD + j] = wv.w;
    }
    __syncthreads();
#pragma unroll 4
    for (int dd = 0; dd < 64; dd += 4) {
      float4 ws[4];
#pragma unroll
      for (int dk = 0; dk < 4; ++dk)
        ws[dk] = *reinterpret_cast<const float4*>(&WL[(dd + dk) * PAD + 4 * tx]);
      float4 x0 = *reinterpret_cast<const float4*>(&XT[ty * PAD + dd]);
      float4 x1 = *reinterpret_cast<const float4*>(&XT[(ty + 32) * PAD + dd]);
      float xm0[4] = {x0.x, x0.y, x0.z, x0.w};
      float xm1[4] = {x1.x, x1.y, x1.z, x1.w};
#pragma unroll
      for (int dk = 0; dk < 4; ++dk) {
        acc[0][0] = fmaf(xm0[dk], ws[dk].x, acc[0][0]);
        acc[0][1] = fmaf(xm0[dk], ws[dk].y, acc[0][1]);
        acc[0][2] = fmaf(xm0[dk], ws[dk].z, acc[0][2]);
        acc[0][3] = fmaf(xm0[dk], ws[dk].w, acc[0][3]);
        acc[1][0] = fmaf(xm1[dk], ws[dk].x, acc[1][0]);
        acc[1][1] = fmaf(xm1[dk], ws[dk].y, acc[1][1]);
        acc[1][2] = fmaf(xm1[dk], ws[dk].z, acc[1][2]);
        acc[1][3] = fmaf(xm1[dk], ws[dk].w, acc[1][3]);
      }
    }
  }

#pragma unroll
  for (int mi = 0; mi < 2; ++mi) {
    int n = n0 + mi * 32 + ty;
    if (n < n_nodes) {
      ushort4 o = make_ushort4(f2bf(acc[mi][0]), f2bf(acc[mi][1]),
                               f2bf(acc[mi][2]), f2bf(acc[mi][3]));
      *reinterpret_cast<ushort4*>(&out[(size_t)n * HID + 4 * tx]) = o;
    }
  }
}

// ============ K1: fused build + layer-1 GEMM + WT2 transpose ============
// b < NBLK: edge build, LDS-SORT then COALESCED write-out (round-10: direct
// scatter made every wave-store touch ~64 lines; LDS sort -> ~5). Per-edge
// atomics LDS-only (round-3 lesson: global per-edge atomics = 100MB writeback).
// NBLK <= b < NBLK+ntile: 64x64 gemm1 tile. b == NBLK+ntile: WT2[d][j] = W2[j][d]
// (consumed only by K3, a later launch -> no race).

__global__ __launch_bounds__(512) void k_build_gemm(const int* __restrict__ src,
                                                    const int* __restrict__ dst,
                                                    const float* __restrict__ ew,
                                                    int* __restrict__ cursor,
                                                    int2* __restrict__ bufA,
                                                    int E, int chunk,
                                                    const float* __restrict__ x,
                                                    const float* __restrict__ W1,
                                                    u16* __restrict__ h,
                                                    int n_nodes,
                                                    const float* __restrict__ W2,
                                                    float* __restrict__ WT2,
                                                    int ntile) {
  __shared__ float S[9216];          // gemm: 8704 floats; build: 4096 int2 + 1024 int
  int b = blockIdx.x, tid = threadIdx.x;
  if (b >= NBLK + ntile) {           // WT2 transpose block (tiny)
    for (int i = tid; i < HID * HID; i += 512) {
      int d = i >> 6, j = i & 63;
      WT2[i] = W2[j * HID + d];
    }
    return;
  }
  if (b >= NBLK) {                   // gemm1 tile blocks
    gemm_tile<DIN>(x, W1, h, S, S + 64 * PAD, (b - NBLK) * 64, n_nodes, tid);
    return;
  }
  int2* lbuf  = (int2*)S;            // 4096 records (32KB)
  int*  lhist = (int*)&S[8192];      // 256
  int*  lstart= (int*)&S[8448];      // 256
  int*  lcur  = (int*)&S[8704];      // 256
  int*  gofs  = (int*)&S[8960];      // 256
  if (tid < 256) lhist[tid] = 0;
  __syncthreads();
  int e0 = b * chunk, e1 = min(E, e0 + chunk);   // chunk%4==0, E%4==0 -> (e1-e0)%4==0
  int m = e1 - e0;                               // <= 4096 for E <= 2.09M
  // load <=8 edges/thread into regs + LDS histogram
  int4 s4[2], d4[2];
  float4 w4[2];
  bool val[2];
#pragma unroll
  for (int it = 0; it < 2; ++it) {
    int e = e0 + 4 * (tid + it * 512);
    val[it] = (e < e1) && (e < e0 + 4096);
    if (val[it]) {
      s4[it] = *reinterpret_cast<const int4*>(&src[e]);
      d4[it] = *reinterpret_cast<const int4*>(&dst[e]);
      w4[it] = *reinterpret_cast<const float4*>(&ew[e]);
      atomicAdd(&lhist[d4[it].x >> 8], 1);
      atomicAdd(&lhist[d4[it].y >> 8], 1);
      atomicAdd(&lhist[d4[it].z >> 8], 1);
      atomicAdd(&lhist[d4[it].w >> 8], 1);
    }
  }
  __syncthreads();
  // inclusive Hillis-Steele scan over 256 bins (in place)
  int own = (tid < 256) ? lhist[tid] : 0;
  for (int o = 1; o < 256; o <<= 1) {
    int u = 0;
    if (tid < 256 && tid >= o) u = lhist[tid - o];
    __syncthreads();
    if (tid < 256) lhist[tid] += u;
    __syncthreads();
  }
  if (tid < 256) {
    int excl = lhist[tid] - own;
    lstart[tid] = excl;
    lcur[tid] = excl;
    int g = (own > 0) ? atomicAdd(&cursor[tid], own) : 0;
    gofs[tid] = (tid << CSH) + g - excl;    // final pos = gofs[bkt] + j
  }
  __syncthreads();
  // scatter records into LDS by bucket
#pragma unroll
  for (int it = 0; it < 2; ++it) {
    if (val[it]) {
      int p0 = atomicAdd(&lcur[d4[it].x >> 8], 1);
      lbuf[p0] = make_int2(__float_as_int(w4[it].x),
                           (int)(((unsigned)s4[it].x << 16) | (unsigned)d4[it].x));
      int p1 = atomicAdd(&lcur[d4[it].y >> 8], 1);
      lbuf[p1] = make_int2(__float_as_int(w4[it].y),
                           (int)(((unsigned)s4[it].y << 16) | (unsigned)d4[it].y));
      int p2 = atomicAdd(&lcur[d4[it].z >> 8], 1);
      lbuf[p2] = make_int2(__float_as_int(w4[it].z),
                           (int)(((unsigned)s4[it].z << 16) | (unsigned)d4[it].z));
      int p3 = atomicAdd(&lcur[d4[it].w >> 8], 1);
      lbuf[p3] = make_int2(__float_as_int(w4[it].w),
                           (int)(((unsigned)s4[it].w << 16) | (unsigned)d4[it].w));
    }
  }
  __syncthreads();
  // coalesced write-out: consecutive j -> consecutive global within bucket runs
  int mc = min(m, 4096);
  for (int j = tid; j < mc; j += 512) {
    int2 r = lbuf[j];
    int bkt = (int)(((unsigned)r.y & 0xffffu) >> 8);
    bufA[gofs[bkt] + j] = r;
  }
  // residual path (chunk > 4096; dead for E=1.6M)
  for (int e = e0 + 4096 + tid; e < e1; e += 512) {
    int s = src[e], d = dst[e];
    int g = atomicAdd(&cursor[d >> 8], 1);
    bufA[((d >> 8) << CSH) + g] = make_int2(__float_as_int(ew[e]),
                                            (int)(((unsigned)s << 16) | (unsigned)d));
  }
}

// ============ K2: one block per coarse bucket -> dst-grouped + offs/cnt + dinv ============
// Round-8 form (round-10's sub-chunk LDS sort cost ~3us net — reverted).
// 1024 threads/block; records cached in registers across phases (bufA read ONCE).
// Output record = (w_bits, src); norm factored (w*dinv[src] in agg, *dinv[dst] once).

__global__ __launch_bounds__(1024) void k_passB(const int2* __restrict__ bufA,
                                                const int* __restrict__ cursor,
                                                int2* __restrict__ bufB,
                                                int* __restrict__ offs,
                                                int* __restrict__ cnt,
                                                float* __restrict__ dinv,
                                                int NBC, int N) {
  int bin = blockIdx.x, tid = threadIdx.x;
  __shared__ int h2[256];
  __shared__ int cur[256];
  __shared__ float dg[256];
  int bbase = bin << CSH;
  int m = cursor[bin];
  if (tid < 256) { h2[tid] = 0; dg[tid] = 0.f; }
  __syncthreads();
  // phase 1: fine histogram of dst&255, records cached in registers
  int2 rloc[16];                 // CAP/1024 = 16 max records per thread
#pragma unroll
  for (int k = 0; k < 16; ++k) {
    int i = tid + k * 1024;
    if (i < m) {
      rloc[k] = bufA[bbase + i];
      atomicAdd(&h2[(unsigned)rloc[k].y & 255u], 1);
    }
  }
  __syncthreads();
  int own = (tid < 256) ? h2[tid] : 0;
  // inclusive Hillis-Steele scan over 256 bins
  for (int o = 1; o < 256; o <<= 1) {
    int u = 0;
    if (tid < 256 && tid >= o) u = h2[tid - o];
    __syncthreads();
    if (tid < 256) h2[tid] += u;
    __syncthreads();
  }
  int nd = (bin << 8) + tid;
  if (tid < 256) {
    int excl = h2[tid] - own;
    cur[tid] = excl;
    if (nd < N) { offs[nd] = bbase + excl; cnt[nd] = own; }
  }
  __syncthreads();
  // phase 2: scatter into dst-grouped order as (w, src) + weighted degree
#pragma unroll
  for (int k = 0; k < 16; ++k) {
    int i = tid + k * 1024;
    if (i < m) {
      int2 r = rloc[k];
      unsigned sd = (unsigned)r.y;
      int dl = (int)(sd & 255u);
      int p = atomicAdd(&cur[dl], 1);
      bufB[bbase + p] = make_int2(r.x, (int)(sd >> 16));
      atomicAdd(&dg[dl], __int_as_float(r.x));
    }
  }
  __syncthreads();
  if (tid < 256 && nd < N) dinv[nd] = rsqrtf(1.0f + dg[tid]);  // self-loop w=1; deg>=1
}

// ============ agg core: 8-lane group per node, shfl-shared records, pipelined ====

__device__ __forceinline__ void bfma8(const uint4& v, float w, float* a) {
  a[0] = fmaf(__uint_as_float(v.x << 16), w, a[0]);
  a[1] = fmaf(__uint_as_float(v.x & 0xffff0000u), w, a[1]);
  a[2] = fmaf(__uint_as_float(v.y << 16), w, a[2]);
  a[3] = fmaf(__uint_as_float(v.y & 0xffff0000u), w, a[3]);
  a[4] = fmaf(__uint_as_float(v.z << 16), w, a[4]);
  a[5] = fmaf(__uint_as_float(v.z & 0xffff0000u), w, a[5]);
  a[6] = fmaf(__uint_as_float(v.w << 16), w, a[6]);
  a[7] = fmaf(__uint_as_float(v.w & 0xffff0000u), w, a[7]);
}

// accumulates di*(sum_e w*dinv[s]*h[s] + di*h[node]) into r[8] (pre-bias)
__device__ __forceinline__ void agg_node(const u16* __restrict__ h,
                                         const int2* __restrict__ recs,
                                         const float* __restrict__ dinv,
                                         int beg, int end, int node, float di,
                                         int lane, int p8, float* r) {
  float a[8], b[8];
  {
    uint4 v = *reinterpret_cast<const uint4*>(&h[(size_t)node * HID + p8]);
    a[0] = __uint_as_float(v.x << 16) * di;          // self: di*(di*h) after epilogue
    a[1] = __uint_as_float(v.x & 0xffff0000u) * di;
    a[2] = __uint_as_float(v.y << 16) * di;
    a[3] = __uint_as_float(v.y & 0xffff0000u) * di;
    a[4] = __uint_as_float(v.z << 16) * di;
    a[5] = __uint_as_float(v.z & 0xffff0000u) * di;
    a[6] = __uint_as_float(v.w << 16) * di;
    a[7] = __uint_as_float(v.w & 0xffff0000u) * di;
#pragma unroll
    for (int j = 0; j < 8; ++j) b[j] = 0.f;
  }

  const int gb = lane & 56;           // group base lane
  const int l7 = lane & 7;
  int i = beg;
  if (i + 8 <= end) {
    ull rr = *reinterpret_cast<const ull*>(&recs[i + l7]);
    float dv = dinv[(int)(rr >> 32)];
    for (;;) {
      float wd = __uint_as_float((unsigned)rr) * dv;
      ull ru = (rr & 0xffffffff00000000ull) | (ull)__float_as_uint(wd);
      bool more = (i + 16 <= end);
      ull rr_n = 0; float dv_n = 0.f;
      if (more) {                     // prefetch next iteration's chain
        rr_n = *reinterpret_cast<const ull*>(&recs[i + 8 + l7]);
        dv_n = dinv[(int)(rr_n >> 32)];
      }
#pragma unroll
      for (int k = 0; k < 8; ++k) {
        ull q = __shfl(ru, gb | k, 64);
        float wk = __uint_as_float((unsigned)q);
        int sk = (int)(q >> 32);
        uint4 vk = *reinterpret_cast<const uint4*>(&h[(size_t)sk * HID + p8]);
        bfma8(vk, wk, (k & 1) ? b : a);
      }
      i += 8;
      if (!more) break;
      rr = rr_n; dv = dv_n;
    }
  }
  if (i + 4 <= end) {
    int2 r0 = recs[i];     int2 r1 = recs[i + 1];
    int2 r2 = recs[i + 2]; int2 r3 = recs[i + 3];
    uint4 v0 = *reinterpret_cast<const uint4*>(&h[(size_t)r0.y * HID + p8]);
    uint4 v1 = *reinterpret_cast<const uint4*>(&h[(size_t)r1.y * HID + p8]);
    uint4 v2 = *reinterpret_cast<const uint4*>(&h[(size_t)r2.y * HID + p8]);
    uint4 v3 = *reinterpret_cast<const uint4*>(&h[(size_t)r3.y * HID + p8]);
    bfma8(v0, __int_as_float(r0.x) * dinv[r0.y], a);
    bfma8(v1, __int_as_float(r1.x) * dinv[r1.y], b);
    bfma8(v2, __int_as_float(r2.x) * dinv[r2.y], a);
    bfma8(v3, __int_as_float(r3.x) * dinv[r3.y], b);
    i += 4;
  }
  if (i + 2 <= end) {
    int2 r0 = recs[i];     int2 r1 = recs[i + 1];
    uint4 v0 = *reinterpret_cast<const uint4*>(&h[(size_t)r0.y * HID + p8]);
    uint4 v1 = *reinterpret_cast<const uint4*>(&h[(size_t)r1.y * HID + p8]);
    bfma8(v0, __int_as_float(r0.x) * dinv[r0.y], a);
    bfma8(v1, __int_as_float(r1.x) * dinv[r1.y], b);
    i += 2;
  }
  if (i < end) {
    int2 r0 = recs[i];
    uint4 v0 = *reinterpret_cast<const uint4*>(&h[(size_t)r0.y * HID + p8]);
    bfma8(v0, __int_as_float(r0.x) * dinv[r0.y], a);
  }
#pragma unroll
  for (int j = 0; j < 8; ++j) r[j] = (a[j] + b[j]) * di;   // apply dinv[dst] once
}

// ============ K3: fused agg1 + gemm2 — 256 threads / 32 nodes, LDS = XT only ====
// Round-11: WL eliminated — phase B reads pre-transposed WT2 (16KB) straight from
// global; it is identical for every block so it lives in each CU's 32KB L1.
// LDS 26.1KB -> 8.7KB => 8 blocks/CU (2048-thread cap, was 6 blocks) — more
// resident waves for the latency-bound gather phase (round-10: occ 33%).

__global__ __launch_bounds__(256) void k_agg_gemm(const u16* __restrict__ h,
                                                  const int2* __restrict__ recs,
                                                  const int* __restrict__ offs,
                                                  const int* __restrict__ cnt,
                                                  const float* __restrict__ dinv,
                                                  const float* __restrict__ bias,
                                                  const float* __restrict__ WT2,
                                                  float* __restrict__ h1,
                                                  u16* __restrict__ h2,
                                                  int n_nodes) {
  __shared__ float XT[32 * PAD];
  int tid = threadIdx.x;
  int lane = tid & 63;
  int p8 = (lane & 7) * 8;
  int nl = (tid >> 6) * 8 + (lane >> 3);        // 0..31 local node
  int n0 = blockIdx.x * 32;
  int node = n0 + nl;
  if (node < n_nodes) {
    float di = dinv[node];
    float r[8];
    agg_node(h, recs, dinv, offs[node], offs[node] + cnt[node], node, di,
             lane, p8, r);
    float4 bb0 = *reinterpret_cast<const float4*>(&bias[p8]);
    float4 bb1 = *reinterpret_cast<const float4*>(&bias[p8 + 4]);
    r[0] += bb0.x; r[1] += bb0.y; r[2] += bb0.z; r[3] += bb0.w;
    r[4] += bb1.x; r[5] += bb1.y; r[6] += bb1.z; r[7] += bb1.w;
#pragma unroll
    for (int j = 0; j < 8; ++j) r[j] = fmaxf(r[j], 0.f);
    float4 lo = make_float4(r[0], r[1], r[2], r[3]);
    float4 hi = make_float4(r[4], r[5], r[6], r[7]);
    *reinterpret_cast<float4*>(&h1[(size_t)node * HID + p8]) = lo;
    *reinterpret_cast<float4*>(&h1[(size_t)node * HID + p8 + 4]) = hi;
    *reinterpret_cast<float4*>(&XT[nl * PAD + p8]) = lo;
    *reinterpret_cast<float4*>(&XT[nl * PAD + p8 + 4]) = hi;
  }
  __syncthreads();                    // XT visible to all
  // phase B: 32x64 gemm2, X from LDS, W from global WT2 (L1-hot)
  const int tx = tid & 15;
  const int ty = tid >> 4;            // 0..15
  float acc[2][4] = {{0.f}};
#pragma unroll 4
  for (int dd = 0; dd < 64; dd += 4) {
    float4 ws[4];
#pragma unroll
    for (int dk = 0; dk < 4; ++dk)
      ws[dk] = *reinterpret_cast<const float4*>(&WT2[(dd + dk) * 64 + 4 * tx]);
    float4 x0 = *reinterpret_cast<const float4*>(&XT[ty * PAD + dd]);
    float4 x1 = *reinterpret_cast<const float4*>(&XT[(ty + 16) * PAD + dd]);
    float xm0[4] = {x0.x, x0.y, x0.z, x0.w};
    float xm1[4] = {x1.x, x1.y, x1.z, x1.w};
#pragma unroll
    for (int dk = 0; dk < 4; ++dk) {
      acc[0][0] = fmaf(xm0[dk], ws[dk].x, acc[0][0]);
      acc[0][1] = fmaf(xm0[dk], ws[dk].y, acc[0][1]);
      acc[0][2] = fmaf(xm0[dk], ws[dk].z, acc[0][2]);
      acc[0][3] = fmaf(xm0[dk], ws[dk].w, acc[0][3]);
      acc[1][0] = fmaf(xm1[dk], ws[dk].x, acc[1][0]);
      acc[1][1] = fmaf(xm1[dk], ws[dk].y, acc[1][1]);
      acc[1][2] = fmaf(xm1[dk], ws[dk].z, acc[1][2]);
      acc[1][3] = fmaf(xm1[dk], ws[dk].w, acc[1][3]);
    }
  }
#pragma unroll
  for (int mi = 0; mi < 2; ++mi) {
    int n = n0 + mi * 16 + ty;
    if (n < n_nodes) {
      ushort4 o = make_ushort4(f2bf(acc[mi][0]), f2bf(acc[mi][1]),
                               f2bf(acc[mi][2]), f2bf(acc[mi][3]));
      *reinterpret_cast<ushort4*>(&h2[(size_t)n * HID + 4 * tx]) = o;
    }
  }
}

// ============ K4: final aggregation (layer 2) ============
// out = di*(sum w*dinv[s]*h2[s] + di*h2[node]) + b2 + h1

__global__ __launch_bounds__(256) void k_agg2(const u16* __restrict__ h,
                                              const int2* __restrict__ recs,
                                              const int* __restrict__ offs,
                                              const int* __restrict__ cnt,
                                              const float* __restrict__ dinv,
                                              const float* __restrict__ bias,
                                              const float* __restrict__ resid,
                                              float* __restrict__ out, int n_nodes) {
  int tid = threadIdx.x;
  int lane = tid & 63;
  int p8 = (lane & 7) * 8;
  int node = (blockIdx.x * 4 + (tid >> 6)) * 8 + (lane >> 3);   // 32 nodes/block
  if (node >= n_nodes) return;
  float di = dinv[node];
  float r[8];
  agg_node(h, recs, dinv, offs[node], offs[node] + cnt[node], node, di,
           lane, p8, r);
  float4 bb0 = *reinterpret_cast<const float4*>(&bias[p8]);
  float4 bb1 = *reinterpret_cast<const float4*>(&bias[p8 + 4]);
  float4 rs0 = *reinterpret_cast<const float4*>(&resid[(size_t)node * HID + p8]);
  float4 rs1 = *reinterpret_cast<const float4*>(&resid[(size_t)node * HID + p8 + 4]);
  r[0] += bb0.x + rs0.x; r[1] += bb0.y + rs0.y;
  r[2] += bb0.z + rs0.z; r[3] += bb0.w + rs0.w;
  r[4] += bb1.x + rs1.x; r[5] += bb1.y + rs1.y;
  r[6] += bb1.z + rs1.z; r[7] += bb1.w + rs1.w;
  *reinterpret_cast<float4*>(&out[(size_t)node * HID + p8]) =
      make_float4(r[0], r[1], r[2], r[3]);
  *reinterpret_cast<float4*>(&out[(size_t)node * HID + p8 + 4]) =
      make_float4(r[4], r[5], r[6], r[7]);
}

// ============ launcher ============

extern "C" void kernel_launch(void* const* d_in, const int* in_sizes, int n_in,
                              void* d_out, int out_size, void* d_ws, size_t ws_size,
                              hipStream_t stream) {
  const float* x  = (const float*)d_in[0];
  const int*   ei = (const int*)d_in[1];
  const float* ew = (const float*)d_in[2];
  const float* W1 = (const float*)d_in[3];
  const float* b1 = (const float*)d_in[4];
  const float* W2 = (const float*)d_in[5];
  const float* b2 = (const float*)d_in[6];
  float* out = (float*)d_out;

  const int N = in_sizes[0] / DIN;
  const int E = in_sizes[2];
  const int* src = ei;        // ei shape (2,E) row-major
  const int* dst = ei + E;

  const int NBC = (N + 255) >> 8;          // coarse buckets (196 for N=50000)
  const int chunk = (((E + NBLK - 1) / NBLK) + 3) & ~3;   // multiple of 4 -> int4 loads
  const int nslab = NBC << CSH;            // total slab entries

  char* p = (char*)d_ws;
  auto carve = [&](size_t bytes) {
    char* r = p;
    p += (bytes + 255) & ~(size_t)255;
    return r;
  };
  int*   cursor = (int*)carve(256 * 4);
  int*   offs   = (int*)carve((size_t)N * 4);
  int*   cnt    = (int*)carve((size_t)N * 4);
  float* dinv   = (float*)carve((size_t)N * 4);
  int2*  bufA   = (int2*)carve((size_t)nslab * 8);
  int2*  bufB   = (int2*)carve((size_t)nslab * 8);
  u16*   h      = (u16*)carve((size_t)N * HID * 2);   // bf16 gemm1 output
  u16*   h2     = (u16*)carve((size_t)N * HID * 2);   // bf16 gemm2 output
  float* h1     = (float*)carve((size_t)N * HID * 4); // fp32 layer-1 activations
  float* WT2    = (float*)carve((size_t)HID * HID * 4);

  int gblk  = (N + 63) / 64;                  // 64-node gemm1 tiles (782)
  int gblk2 = (N + 31) / 32;                  // 32-node agg_gemm blocks (1563)
  int ablk  = (N + 31) / 32;                  // 32 nodes per 256-thread block

  // ---- K1: build (edges) + gemm1 + WT2 transpose in one launch ----
  hipMemsetAsync(cursor, 0, 256 * 4, stream);
  k_build_gemm<<<NBLK + gblk + 1, 512, 0, stream>>>(src, dst, ew, cursor, bufA, E,
                                                    chunk, x, W1, h, N, W2, WT2, gblk);
  // ---- K2: bucket sort -> dst-grouped records + dinv ----
  k_passB<<<NBC, 1024, 0, stream>>>(bufA, cursor, bufB, offs, cnt, dinv, NBC, N);
  // ---- K3: agg1 (+bias,relu) fused with gemm2 (WT2 from L1) ----
  k_agg_gemm<<<gblk2, 256, 0, stream>>>(h, bufB, offs, cnt, dinv, b1, WT2, h1, h2, N);
  // ---- K4: agg2 + bias + resid -> out ----
  k_agg2<<<ablk, 256, 0, stream>>>(h2, bufB, offs, cnt, dinv, b2, h1, out, N);
}

// Round 12
// 208.752 us; speedup vs baseline: 1.0290x; 1.0290x over previous
//
#include <hip/hip_runtime.h>

#define HID 64
#define DIN 128
#define NBLK 512                // blocks for the build pass
#define CSH 14                  // slab capacity shift: 16384 entries per bucket
#define CAP (1 << CSH)
#define PAD 68                  // float4-aligned LDS row stride

typedef unsigned long long ull;
typedef unsigned short u16;

static __device__ __forceinline__ u16 f2bf(float f) {
  unsigned u = __float_as_uint(f);
  unsigned lsb = (u >> 16) & 1u;
  u += 0x7fffu + lsb;
  return (u16)(u >> 16);
}

// ============ shared gemm tile: NT threads, (NT/8)x64 output, self-transposing W ====
// W staging lane map: qd wave-uniform, j lane-sweep -> each transpose write hits 64
// consecutive floats of one LDS row = 2 lanes/bank, conflict-free (round-7 fix).
// XT_PRELOADED: XT filled by caller (fused agg epilogue) -> skip X staging.
// NOTE (round-11 lesson): keeping W in LDS (WL) is FASTER than reading a
// pre-transposed W from global/L1 in the inner loop (40.8 vs 47.5 us) — K3's
// occupancy is straggler-capped, not LDS-capped, so spending LDS on WL is free.

template <int K, int NT, bool XT_PRELOADED>
__device__ __forceinline__ void gemm_tile(const float* __restrict__ X,
                                          const float* __restrict__ W,
                                          u16* __restrict__ out,
                                          float* XT, float* WL,
                                          int n0, int n_nodes, int tid) {
  constexpr int ROWS = NT / 8;            // 64 (NT=512) or 32 (NT=256)
  const int tx = tid & 15;
  const int ty = tid >> 4;                // 0..NT/16-1
  float acc[2][4] = {{0.f}};

  for (int ph = 0; ph < K / 64; ++ph) {
    const int d0 = ph * 64;
    __syncthreads();
    if (!XT_PRELOADED) {
#pragma unroll
      for (int k = 0; k < 2; ++k) {       // ROWS*16 slots = NT*2
        int f = tid + k * NT;
        int r = f >> 4, q = f & 15;
        int n = n0 + r;
        float4 xv = (n < n_nodes)
          ? *reinterpret_cast<const float4*>(&X[(size_t)n * K + d0 + 4 * q])
          : make_float4(0.f, 0.f, 0.f, 0.f);
        *reinterpret_cast<float4*>(&XT[r * PAD + 4 * q]) = xv;
      }
    }
#pragma unroll
    for (int k = 0; k < 1024 / NT; ++k) { // 1024 slots: 16 d-quads x 64 j
      int gq = tid + k * NT;
      int qd = gq >> 6, j = gq & 63;
      float4 wv = *reinterpret_cast<const float4*>(&W[(size_t)j * K + d0 + 4 * qd]);
      WL[(4 * qd + 0) * PAD + j] = wv.x;
      WL[(4 * qd + 1) * PAD + j] = wv.y;
      WL[(4 * qd + 2) * PAD + j] = wv.z;
      WL[(4 * qd + 3) * PAD + j] = wv.w;
    }
    __syncthreads();
#pragma unroll 4
    for (int dd = 0; dd < 64; dd += 4) {
      float4 ws[4];
#pragma unroll
      for (int dk = 0; dk < 4; ++dk)
        ws[dk] = *reinterpret_cast<const float4*>(&WL[(dd + dk) * PAD + 4 * tx]);
      float4 x0 = *reinterpret_cast<const float4*>(&XT[ty * PAD + dd]);
      float4 x1 = *reinterpret_cast<const float4*>(&XT[(ty + ROWS / 2) * PAD + dd]);
      float xm0[4] = {x0.x, x0.y, x0.z, x0.w};
      float xm1[4] = {x1.x, x1.y, x1.z, x1.w};
#pragma unroll
      for (int dk = 0; dk < 4; ++dk) {
        acc[0][0] = fmaf(xm0[dk], ws[dk].x, acc[0][0]);
        acc[0][1] = fmaf(xm0[dk], ws[dk].y, acc[0][1]);
        acc[0][2] = fmaf(xm0[dk], ws[dk].z, acc[0][2]);
        acc[0][3] = fmaf(xm0[dk], ws[dk].w, acc[0][3]);
        acc[1][0] = fmaf(xm1[dk], ws[dk].x, acc[1][0]);
        acc[1][1] = fmaf(xm1[dk], ws[dk].y, acc[1][1]);
        acc[1][2] = fmaf(xm1[dk], ws[dk].z, acc[1][2]);
        acc[1][3] = fmaf(xm1[dk], ws[dk].w, acc[1][3]);
      }
    }
  }

#pragma unroll
  for (int mi = 0; mi < 2; ++mi) {
    int n = n0 + mi * (ROWS / 2) + ty;
    if (n < n_nodes) {
      ushort4 o = make_ushort4(f2bf(acc[mi][0]), f2bf(acc[mi][1]),
                               f2bf(acc[mi][2]), f2bf(acc[mi][3]));
      *reinterpret_cast<ushort4*>(&out[(size_t)n * HID + 4 * tx]) = o;
    }
  }
}

// ============ K1: fused build + layer-1 GEMM (independent block roles) ============
// b < NBLK: edge build, LDS-SORT then COALESCED write-out (round-10 win: direct
// scatter made every wave-store touch ~64 lines; LDS sort -> ~5, 43.7->41.6us).
// Per-edge atomics LDS-only (round-3 lesson: global per-edge atomics = 100MB
// writeback). b >= NBLK: 64x64 gemm1 tile h = x@W1^T.

__global__ __launch_bounds__(512) void k_build_gemm(const int* __restrict__ src,
                                                    const int* __restrict__ dst,
                                                    const float* __restrict__ ew,
                                                    int* __restrict__ cursor,
                                                    int2* __restrict__ bufA,
                                                    int E, int chunk,
                                                    const float* __restrict__ x,
                                                    const float* __restrict__ W1,
                                                    u16* __restrict__ h,
                                                    int n_nodes) {
  __shared__ float S[9216];          // gemm: 8704 floats; build: 4096 int2 + 1024 int
  int b = blockIdx.x, tid = threadIdx.x;
  if (b >= NBLK) {                   // gemm1 tile blocks
    gemm_tile<DIN, 512, false>(x, W1, h, S, S + 64 * PAD, (b - NBLK) * 64, n_nodes, tid);
    return;
  }
  int2* lbuf  = (int2*)S;            // 4096 records (32KB)
  int*  lhist = (int*)&S[8192];      // 256
  int*  lstart= (int*)&S[8448];      // 256
  int*  lcur  = (int*)&S[8704];      // 256
  int*  gofs  = (int*)&S[8960];      // 256
  if (tid < 256) lhist[tid] = 0;
  __syncthreads();
  int e0 = b * chunk, e1 = min(E, e0 + chunk);   // chunk%4==0, E%4==0 -> (e1-e0)%4==0
  int m = e1 - e0;                               // <= 4096 for E <= 2.09M
  // load <=8 edges/thread into regs + LDS histogram
  int4 s4[2], d4[2];
  float4 w4[2];
  bool val[2];
#pragma unroll
  for (int it = 0; it < 2; ++it) {
    int e = e0 + 4 * (tid + it * 512);
    val[it] = (e < e1) && (e < e0 + 4096);
    if (val[it]) {
      s4[it] = *reinterpret_cast<const int4*>(&src[e]);
      d4[it] = *reinterpret_cast<const int4*>(&dst[e]);
      w4[it] = *reinterpret_cast<const float4*>(&ew[e]);
      atomicAdd(&lhist[d4[it].x >> 8], 1);
      atomicAdd(&lhist[d4[it].y >> 8], 1);
      atomicAdd(&lhist[d4[it].z >> 8], 1);
      atomicAdd(&lhist[d4[it].w >> 8], 1);
    }
  }
  __syncthreads();
  // inclusive Hillis-Steele scan over 256 bins (in place)
  int own = (tid < 256) ? lhist[tid] : 0;
  for (int o = 1; o < 256; o <<= 1) {
    int u = 0;
    if (tid < 256 && tid >= o) u = lhist[tid - o];
    __syncthreads();
    if (tid < 256) lhist[tid] += u;
    __syncthreads();
  }
  if (tid < 256) {
    int excl = lhist[tid] - own;
    lstart[tid] = excl;
    lcur[tid] = excl;
    int g = (own > 0) ? atomicAdd(&cursor[tid], own) : 0;
    gofs[tid] = (tid << CSH) + g - excl;    // final pos = gofs[bkt] + j
  }
  __syncthreads();
  // scatter records into LDS by bucket
#pragma unroll
  for (int it = 0; it < 2; ++it) {
    if (val[it]) {
      int p0 = atomicAdd(&lcur[d4[it].x >> 8], 1);
      lbuf[p0] = make_int2(__float_as_int(w4[it].x),
                           (int)(((unsigned)s4[it].x << 16) | (unsigned)d4[it].x));
      int p1 = atomicAdd(&lcur[d4[it].y >> 8], 1);
      lbuf[p1] = make_int2(__float_as_int(w4[it].y),
                           (int)(((unsigned)s4[it].y << 16) | (unsigned)d4[it].y));
      int p2 = atomicAdd(&lcur[d4[it].z >> 8], 1);
      lbuf[p2] = make_int2(__float_as_int(w4[it].z),
                           (int)(((unsigned)s4[it].z << 16) | (unsigned)d4[it].z));
      int p3 = atomicAdd(&lcur[d4[it].w >> 8], 1);
      lbuf[p3] = make_int2(__float_as_int(w4[it].w),
                           (int)(((unsigned)s4[it].w << 16) | (unsigned)d4[it].w));
    }
  }
  __syncthreads();
  // coalesced write-out: consecutive j -> consecutive global within bucket runs
  int mc = min(m, 4096);
  for (int j = tid; j < mc; j += 512) {
    int2 r = lbuf[j];
    int bkt = (int)(((unsigned)r.y & 0xffffu) >> 8);
    bufA[gofs[bkt] + j] = r;
  }
  // residual path (chunk > 4096; dead for E=1.6M)
  for (int e = e0 + 4096 + tid; e < e1; e += 512) {
    int s = src[e], d = dst[e];
    int g = atomicAdd(&cursor[d >> 8], 1);
    bufA[((d >> 8) << CSH) + g] = make_int2(__float_as_int(ew[e]),
                                            (int)(((unsigned)s << 16) | (unsigned)d));
  }
}

// ============ K2: one block per coarse bucket -> dst-grouped + offs/cnt + dinv ============
// Round-8 form exactly (r10's sub-chunk LDS sort cost ~3us net — reverted).
// 1024 threads/block; records cached in registers across phases (bufA read ONCE).
// Output record = (w_bits, src); norm factored (w*dinv[src] in agg, *dinv[dst] once).

__global__ __launch_bounds__(1024) void k_passB(const int2* __restrict__ bufA,
                                                const int* __restrict__ cursor,
                                                int2* __restrict__ bufB,
                                                int* __restrict__ offs,
                                                int* __restrict__ cnt,
                                                float* __restrict__ dinv,
                                                int NBC, int N) {
  int bin = blockIdx.x, tid = threadIdx.x;
  __shared__ int h2[256];
  __shared__ int cur[256];
  __shared__ float dg[256];
  int bbase = bin << CSH;
  int m = cursor[bin];
  if (tid < 256) { h2[tid] = 0; dg[tid] = 0.f; }
  __syncthreads();
  // phase 1: fine histogram of dst&255, records cached in registers
  int2 rloc[16];                 // CAP/1024 = 16 max records per thread
#pragma unroll
  for (int k = 0; k < 16; ++k) {
    int i = tid + k * 1024;
    if (i < m) {
      rloc[k] = bufA[bbase + i];
      atomicAdd(&h2[(unsigned)rloc[k].y & 255u], 1);
    }
  }
  __syncthreads();
  int own = (tid < 256) ? h2[tid] : 0;
  // inclusive Hillis-Steele scan over 256 bins
  for (int o = 1; o < 256; o <<= 1) {
    int u = 0;
    if (tid < 256 && tid >= o) u = h2[tid - o];
    __syncthreads();
    if (tid < 256) h2[tid] += u;
    __syncthreads();
  }
  int nd = (bin << 8) + tid;
  if (tid < 256) {
    int excl = h2[tid] - own;
    cur[tid] = excl;
    if (nd < N) { offs[nd] = bbase + excl; cnt[nd] = own; }
  }
  __syncthreads();
  // phase 2: scatter into dst-grouped order as (w, src) + weighted degree
#pragma unroll
  for (int k = 0; k < 16; ++k) {
    int i = tid + k * 1024;
    if (i < m) {
      int2 r = rloc[k];
      unsigned sd = (unsigned)r.y;
      int dl = (int)(sd & 255u);
      int p = atomicAdd(&cur[dl], 1);
      bufB[bbase + p] = make_int2(r.x, (int)(sd >> 16));
      atomicAdd(&dg[dl], __int_as_float(r.x));
    }
  }
  __syncthreads();
  if (tid < 256 && nd < N) dinv[nd] = rsqrtf(1.0f + dg[tid]);  // self-loop w=1; deg>=1
}

// ============ agg core: 8-lane group per node, shfl-shared records, pipelined ====

__device__ __forceinline__ void bfma8(const uint4& v, float w, float* a) {
  a[0] = fmaf(__uint_as_float(v.x << 16), w, a[0]);
  a[1] = fmaf(__uint_as_float(v.x & 0xffff0000u), w, a[1]);
  a[2] = fmaf(__uint_as_float(v.y << 16), w, a[2]);
  a[3] = fmaf(__uint_as_float(v.y & 0xffff0000u), w, a[3]);
  a[4] = fmaf(__uint_as_float(v.z << 16), w, a[4]);
  a[5] = fmaf(__uint_as_float(v.z & 0xffff0000u), w, a[5]);
  a[6] = fmaf(__uint_as_float(v.w << 16), w, a[6]);
  a[7] = fmaf(__uint_as_float(v.w & 0xffff0000u), w, a[7]);
}

// accumulates di*(sum_e w*dinv[s]*h[s] + di*h[node]) into r[8] (pre-bias)
__device__ __forceinline__ void agg_node(const u16* __restrict__ h,
                                         const int2* __restrict__ recs,
                                         const float* __restrict__ dinv,
                                         int beg, int end, int node, float di,
                                         int lane, int p8, float* r) {
  float a[8], b[8];
  {
    uint4 v = *reinterpret_cast<const uint4*>(&h[(size_t)node * HID + p8]);
    a[0] = __uint_as_float(v.x << 16) * di;          // self: di*(di*h) after epilogue
    a[1] = __uint_as_float(v.x & 0xffff0000u) * di;
    a[2] = __uint_as_float(v.y << 16) * di;
    a[3] = __uint_as_float(v.y & 0xffff0000u) * di;
    a[4] = __uint_as_float(v.z << 16) * di;
    a[5] = __uint_as_float(v.z & 0xffff0000u) * di;
    a[6] = __uint_as_float(v.w << 16) * di;
    a[7] = __uint_as_float(v.w & 0xffff0000u) * di;
#pragma unroll
    for (int j = 0; j < 8; ++j) b[j] = 0.f;
  }

  const int gb = lane & 56;           // group base lane
  const int l7 = lane & 7;
  int i = beg;
  if (i + 8 <= end) {
    ull rr = *reinterpret_cast<const ull*>(&recs[i + l7]);
    float dv = dinv[(int)(rr >> 32)];
    for (;;) {
      float wd = __uint_as_float((unsigned)rr) * dv;
      ull ru = (rr & 0xffffffff00000000ull) | (ull)__float_as_uint(wd);
      bool more = (i + 16 <= end);
      ull rr_n = 0; float dv_n = 0.f;
      if (more) {                     // prefetch next iteration's chain
        rr_n = *reinterpret_cast<const ull*>(&recs[i + 8 + l7]);
        dv_n = dinv[(int)(rr_n >> 32)];
      }
#pragma unroll
      for (int k = 0; k < 8; ++k) {
        ull q = __shfl(ru, gb | k, 64);
        float wk = __uint_as_float((unsigned)q);
        int sk = (int)(q >> 32);
        uint4 vk = *reinterpret_cast<const uint4*>(&h[(size_t)sk * HID + p8]);
        bfma8(vk, wk, (k & 1) ? b : a);
      }
      i += 8;
      if (!more) break;
      rr = rr_n; dv = dv_n;
    }
  }
  if (i + 4 <= end) {
    int2 r0 = recs[i];     int2 r1 = recs[i + 1];
    int2 r2 = recs[i + 2]; int2 r3 = recs[i + 3];
    uint4 v0 = *reinterpret_cast<const uint4*>(&h[(size_t)r0.y * HID + p8]);
    uint4 v1 = *reinterpret_cast<const uint4*>(&h[(size_t)r1.y * HID + p8]);
    uint4 v2 = *reinterpret_cast<const uint4*>(&h[(size_t)r2.y * HID + p8]);
    uint4 v3 = *reinterpret_cast<const uint4*>(&h[(size_t)r3.y * HID + p8]);
    bfma8(v0, __int_as_float(r0.x) * dinv[r0.y], a);
    bfma8(v1, __int_as_float(r1.x) * dinv[r1.y], b);
    bfma8(v2, __int_as_float(r2.x) * dinv[r2.y], a);
    bfma8(v3, __int_as_float(r3.x) * dinv[r3.y], b);
    i += 4;
  }
  if (i + 2 <= end) {
    int2 r0 = recs[i];     int2 r1 = recs[i + 1];
    uint4 v0 = *reinterpret_cast<const uint4*>(&h[(size_t)r0.y * HID + p8]);
    uint4 v1 = *reinterpret_cast<const uint4*>(&h[(size_t)r1.y * HID + p8]);
    bfma8(v0, __int_as_float(r0.x) * dinv[r0.y], a);
    bfma8(v1, __int_as_float(r1.x) * dinv[r1.y], b);
    i += 2;
  }
  if (i < end) {
    int2 r0 = recs[i];
    uint4 v0 = *reinterpret_cast<const uint4*>(&h[(size_t)r0.y * HID + p8]);
    bfma8(v0, __int_as_float(r0.x) * dinv[r0.y], a);
  }
#pragma unroll
  for (int j = 0; j < 8; ++j) r[j] = (a[j] + b[j]) * di;   // apply dinv[dst] once
}

// ============ K3: fused agg1 + gemm2 — 256 threads / 32 nodes (round-8 form) ====
// Phase A: 4 waves aggregate h1 = relu(conv1+b1) -> h1 (global, resid) + XT (LDS).
// Phase B: 32x64 gemm2 from LDS with WL-in-LDS W staging (round-11 lesson:
// global/L1 W reads in the inner loop cost +7us; occupancy is straggler-capped,
// so LDS spent on WL is free). h2 separate buffer (in-place h would race).

__global__ __launch_bounds__(256) void k_agg_gemm(const u16* __restrict__ h,
                                                  const int2* __restrict__ recs,
                                                  const int* __restrict__ offs,
                                                  const int* __restrict__ cnt,
                                                  const float* __restrict__ dinv,
                                                  const float* __restrict__ bias,
                                                  const float* __restrict__ W2,
                                                  float* __restrict__ h1,
                                                  u16* __restrict__ h2,
                                                  int n_nodes) {
  __shared__ float S[(32 + 64) * PAD];
  float* XT = S;
  float* WL = S + 32 * PAD;
  int tid = threadIdx.x;
  int lane = tid & 63;
  int p8 = (lane & 7) * 8;
  int nl = (tid >> 6) * 8 + (lane >> 3);        // 0..31 local node
  int node = blockIdx.x * 32 + nl;
  if (node < n_nodes) {
    float di = dinv[node];
    float r[8];
    agg_node(h, recs, dinv, offs[node], offs[node] + cnt[node], node, di,
             lane, p8, r);
    float4 bb0 = *reinterpret_cast<const float4*>(&bias[p8]);
    float4 bb1 = *reinterpret_cast<const float4*>(&bias[p8 + 4]);
    r[0] += bb0.x; r[1] += bb0.y; r[2] += bb0.z; r[3] += bb0.w;
    r[4] += bb1.x; r[5] += bb1.y; r[6] += bb1.z; r[7] += bb1.w;
#pragma unroll
    for (int j = 0; j < 8; ++j) r[j] = fmaxf(r[j], 0.f);
    float4 lo = make_float4(r[0], r[1], r[2], r[3]);
    float4 hi = make_float4(r[4], r[5], r[6], r[7]);
    *reinterpret_cast<float4*>(&h1[(size_t)node * HID + p8]) = lo;
    *reinterpret_cast<float4*>(&h1[(size_t)node * HID + p8 + 4]) = hi;
    *reinterpret_cast<float4*>(&XT[nl * PAD + p8]) = lo;
    *reinterpret_cast<float4*>(&XT[nl * PAD + p8 + 4]) = hi;
  }
  // Phase B (all threads; gemm_tile starts with __syncthreads covering XT writes)
  gemm_tile<HID, 256, true>(nullptr, W2, h2, XT, WL, blockIdx.x * 32, n_nodes, tid);
}

// ============ K4: final aggregation (layer 2) ============
// out = di*(sum w*dinv[s]*h2[s] + di*h2[node]) + b2 + h1

__global__ __launch_bounds__(256) void k_agg2(const u16* __restrict__ h,
                                              const int2* __restrict__ recs,
                                              const int* __restrict__ offs,
                                              const int* __restrict__ cnt,
                                              const float* __restrict__ dinv,
                                              const float* __restrict__ bias,
                                              const float* __restrict__ resid,
                                              float* __restrict__ out, int n_nodes) {
  int tid = threadIdx.x;
  int lane = tid & 63;
  int p8 = (lane & 7) * 8;
  int node = (blockIdx.x * 4 + (tid >> 6)) * 8 + (lane >> 3);   // 32 nodes/block
  if (node >= n_nodes) return;
  float di = dinv[node];
  float r[8];
  agg_node(h, recs, dinv, offs[node], offs[node] + cnt[node], node, di,
           lane, p8, r);
  float4 bb0 = *reinterpret_cast<const float4*>(&bias[p8]);
  float4 bb1 = *reinterpret_cast<const float4*>(&bias[p8 + 4]);
  float4 rs0 = *reinterpret_cast<const float4*>(&resid[(size_t)node * HID + p8]);
  float4 rs1 = *reinterpret_cast<const float4*>(&resid[(size_t)node * HID + p8 + 4]);
  r[0] += bb0.x + rs0.x; r[1] += bb0.y + rs0.y;
  r[2] += bb0.z + rs0.z; r[3] += bb0.w + rs0.w;
  r[4] += bb1.x + rs1.x; r[5] += bb1.y + rs1.y;
  r[6] += bb1.z + rs1.z; r[7] += bb1.w + rs1.w;
  *reinterpret_cast<float4*>(&out[(size_t)node * HID + p8]) =
      make_float4(r[0], r[1], r[2], r[3]);
  *reinterpret_cast<float4*>(&out[(size_t)node * HID + p8 + 4]) =
      make_float4(r[4], r[5], r[6], r[7]);
}

// ============ launcher ============

extern "C" void kernel_launch(void* const* d_in, const int* in_sizes, int n_in,
                              void* d_out, int out_size, void* d_ws, size_t ws_size,
                              hipStream_t stream) {
  const float* x  = (const float*)d_in[0];
  const int*   ei = (const int*)d_in[1];
  const float* ew = (const float*)d_in[2];
  const float* W1 = (const float*)d_in[3];
  const float* b1 = (const float*)d_in[4];
  const float* W2 = (const float*)d_in[5];
  const float* b2 = (const float*)d_in[6];
  float* out = (float*)d_out;

  const int N = in_sizes[0] / DIN;
  const int E = in_sizes[2];
  const int* src = ei;        // ei shape (2,E) row-major
  const int* dst = ei + E;

  const int NBC = (N + 255) >> 8;          // coarse buckets (196 for N=50000)
  const int chunk = (((E + NBLK - 1) / NBLK) + 3) & ~3;   // multiple of 4 -> int4 loads
  const int nslab = NBC << CSH;            // total slab entries

  char* p = (char*)d_ws;
  auto carve = [&](size_t bytes) {
    char* r = p;
    p += (bytes + 255) & ~(size_t)255;
    return r;
  };
  int*   cursor = (int*)carve(256 * 4);
  int*   offs   = (int*)carve((size_t)N * 4);
  int*   cnt    = (int*)carve((size_t)N * 4);
  float* dinv   = (float*)carve((size_t)N * 4);
  int2*  bufA   = (int2*)carve((size_t)nslab * 8);
  int2*  bufB   = (int2*)carve((size_t)nslab * 8);
  u16*   h      = (u16*)carve((size_t)N * HID * 2);   // bf16 gemm1 output
  u16*   h2     = (u16*)carve((size_t)N * HID * 2);   // bf16 gemm2 output
  float* h1     = (float*)carve((size_t)N * HID * 4); // fp32 layer-1 activations

  int gblk  = (N + 63) / 64;                  // 64-node gemm1 tiles (782)
  int gblk2 = (N + 31) / 32;                  // 32-node agg_gemm blocks (1563)
  int ablk  = (N + 31) / 32;                  // 32 nodes per 256-thread block

  // ---- K1: build (edges) + gemm1 (independent) in one launch ----
  hipMemsetAsync(cursor, 0, 256 * 4, stream);
  k_build_gemm<<<NBLK + gblk, 512, 0, stream>>>(src, dst, ew, cursor, bufA, E, chunk,
                                                x, W1, h, N);
  // ---- K2: bucket sort -> dst-grouped records + dinv ----
  k_passB<<<NBC, 1024, 0, stream>>>(bufA, cursor, bufB, offs, cnt, dinv, NBC, N);
  // ---- K3: agg1 (+bias,relu) fused with gemm2 ----
  k_agg_gemm<<<gblk2, 256, 0, stream>>>(h, bufB, offs, cnt, dinv, b1, W2, h1, h2, N);
  // ---- K4: agg2 + bias + resid -> out ----
  k_agg2<<<ablk, 256, 0, stream>>>(h2, bufB, offs, cnt, dinv, b2, h1, out, N);
}